// Round 9
// baseline (78.852 us; speedup 1.0000x reference)
//
#include <hip/hip_runtime.h>
#include <math.h>

#define NQ 12
#define DIM 4096

// CNOT ring CNOT(0,1)..CNOT(10,11),CNOT(11,0); wire w <-> bit (11-w).
// F: amplitude at i lands at F(i) (verified r1-r7).  Bits of G = F^{-1}:
//   g_p = i_p ^ i_{p+1} (p=0..9), g_10 = i_10^i_11^i_0, g_11 = i_11^i_0.
__host__ __device__ constexpr int Fmap(int y){
  int s = y ^ (y>>1); s ^= s>>2; s ^= s>>4; s ^= s>>8;
  return (s ^ ((s&1)<<11)) & 0xFFF;
}

__device__ __forceinline__ float sgnf(float M, int bitv){
  return __int_as_float(__float_as_int(M) ^ (bitv<<31));
}

// Fused 2x2 complex gate on owned bit J (round-3/5 verified, explicit FMA).
template<int J>
__device__ __forceinline__ void gate_on_bit(float2 (&s)[16], const float* __restrict__ u){
  const float u00x=u[0], u00y=u[1], u01x=u[2], u01y=u[3];
  const float u10x=u[4], u10y=u[5], u11x=u[6], u11y=u[7];
#pragma unroll
  for (int k = 0; k < 16; ++k){
    if (k & (1 << J)) continue;
    const int k1 = k | (1 << J);
    const float ax = s[k].x, ay = s[k].y, bx = s[k1].x, by = s[k1].y;
    s[k].x  = fmaf(u00x, ax, fmaf(-u00y, ay, fmaf(u01x, bx, -u01y*by)));
    s[k].y  = fmaf(u00x, ay, fmaf( u00y, ax, fmaf(u01x, by,  u01y*bx)));
    s[k1].x = fmaf(u10x, ax, fmaf(-u10y, ay, fmaf(u11x, bx, -u11y*by)));
    s[k1].y = fmaf(u10x, ay, fmaf( u10y, ax, fmaf(u11x, by,  u11y*bx)));
  }
}

__global__ __launch_bounds__(256)
void qsim_kernel(const float* __restrict__ x, const float* __restrict__ wts,
                 float* __restrict__ out){
  __shared__ float2 st[DIM];                   // 32 KB state / reduction scratch
  __shared__ __align__(16) float U1s[12*8];    // layer-1 fused matrices
  __shared__ __align__(16) float4 Qs[NQ];      // post-L0 per-qubit 2-vectors
  float* red = (float*)st;
  char*  stb = (char*)st;
  const int tid  = threadIdx.x;
  const int lane = tid & 63;
  const int b    = blockIdx.x;

  // ---- in-kernel prep (was prep_gates): lanes 0-23, once per block --------
  if (tid < 24){
    const int l = tid / 12, q = tid % 12;
    const float ax = 0.5f * wts[l*36 + q*3 + 0];
    const float ay = 0.5f * wts[l*36 + q*3 + 1];
    const float az = 0.5f * wts[l*36 + q*3 + 2];
    const float ca = cosf(ax), sa = sinf(ax);
    const float cb = cosf(ay), sb = sinf(ay);
    const float cc = cosf(az), sc = sinf(az);
    const float m00x =  cb*ca, m00y =  sb*sa;
    const float m01x = -sb*ca, m01y = -cb*sa;
    const float m10x =  sb*ca, m10y = -cb*sa;
    const float m11x =  cb*ca, m11y = -sb*sa;
    float o0 = cc*m00x + sc*m00y, o1 = cc*m00y - sc*m00x;
    float o2 = cc*m01x + sc*m01y, o3 = cc*m01y - sc*m01x;
    float o4 = cc*m10x - sc*m10y, o5 = cc*m10y + sc*m10x;
    float o6 = cc*m11x - sc*m11y, o7 = cc*m11y + sc*m11x;
    if (l == 0){
      // fold encoding RY for qubit q: Q = U0 * (c, s); store at p = 11-q
      float c0, s0;
      sincosf(x[b*NQ + q] * 1.5707963267948966f, &s0, &c0);
      Qs[11 - q] = make_float4(fmaf(o0, c0, o2*s0), fmaf(o1, c0, o3*s0),
                               fmaf(o4, c0, o6*s0), fmaf(o5, c0, o7*s0));
    } else {
      float* o = U1s + q*8;
      o[0]=o0; o[1]=o1; o[2]=o2; o[3]=o3; o[4]=o4; o[5]=o5; o[6]=o6; o[7]=o7;
    }
  }
  __syncthreads();

  // ---- broadcast-read Q (uniform LDS loads, conflict-free) ----------------
  float4 Q[NQ];
#pragma unroll
  for (int p = 0; p < NQ; ++p) Q[p] = Qs[p];

  // ---- build post-ring state directly: s1[i] = prod_p Q[p][g_p(i)] --------
  // ownership A: i = tid | (k<<8); k bit j = state bit 8+j.  (r5 verified)
  const int gt = tid ^ (tid >> 1);          // bit p: tid_p ^ tid_{p+1}
  float bx, by;
  { const int e = gt & 1;
    bx = e ? Q[0].z : Q[0].x;  by = e ? Q[0].w : Q[0].y; }
#pragma unroll
  for (int p = 1; p <= 6; ++p){
    const int e = (gt >> p) & 1;
    const float fx = e ? Q[p].z : Q[p].x, fy = e ? Q[p].w : Q[p].y;
    const float nx = fmaf(bx, fx, -by*fy);
    by = fmaf(bx, fy, by*fx);  bx = nx;
  }
  const int t7 = (tid >> 7) & 1, t0 = tid & 1;
  float bax[2], bay[2];                      // base * Q7[t7^k0]
#pragma unroll
  for (int k0 = 0; k0 < 2; ++k0){
    const int e = t7 ^ k0;
    const float fx = e ? Q[7].z : Q[7].x, fy = e ? Q[7].w : Q[7].y;
    bax[k0] = fmaf(bx, fx, -by*fy);
    bay[k0] = fmaf(bx, fy,  by*fx);
  }
  float ax2[2][2], ay2[2][2];                // * Q8[k0^k1]
#pragma unroll
  for (int k1 = 0; k1 < 2; ++k1)
#pragma unroll
  for (int k0 = 0; k0 < 2; ++k0){
    const int e = k0 ^ k1;
    const float fx = e ? Q[8].z : Q[8].x, fy = e ? Q[8].w : Q[8].y;
    ax2[k1][k0] = fmaf(bax[k0], fx, -bay[k0]*fy);
    ay2[k1][k0] = fmaf(bax[k0], fy,  bay[k0]*fx);
  }
  float dx[2][2][2], dy[2][2][2];            // * Q9[k1^k2]
#pragma unroll
  for (int k2 = 0; k2 < 2; ++k2)
#pragma unroll
  for (int k1 = 0; k1 < 2; ++k1)
#pragma unroll
  for (int k0 = 0; k0 < 2; ++k0){
    const int e = k1 ^ k2;
    const float fx = e ? Q[9].z : Q[9].x, fy = e ? Q[9].w : Q[9].y;
    dx[k2][k1][k0] = fmaf(ax2[k1][k0], fx, -ay2[k1][k0]*fy);
    dy[k2][k1][k0] = fmaf(ax2[k1][k0], fy,  ay2[k1][k0]*fx);
  }
  float b2x[2][2], b2y[2][2];                // Q10[k2^k3^t0] * Q11[k3^t0]
#pragma unroll
  for (int k3 = 0; k3 < 2; ++k3)
#pragma unroll
  for (int k2 = 0; k2 < 2; ++k2){
    const int e10 = k2 ^ k3 ^ t0, e11 = k3 ^ t0;
    const float gx = e10 ? Q[10].z : Q[10].x, gy = e10 ? Q[10].w : Q[10].y;
    const float hx = e11 ? Q[11].z : Q[11].x, hy = e11 ? Q[11].w : Q[11].y;
    b2x[k3][k2] = fmaf(gx, hx, -gy*hy);
    b2y[k3][k2] = fmaf(gx, hy,  gy*hx);
  }
  float2 s[16];
#pragma unroll
  for (int k = 0; k < 16; ++k){
    const int k0 = k&1, k1 = (k>>1)&1, k2 = (k>>2)&1, k3 = (k>>3)&1;
    s[k].x = fmaf(dx[k2][k1][k0], b2x[k3][k2], -dy[k2][k1][k0]*b2y[k3][k2]);
    s[k].y = fmaf(dx[k2][k1][k0], b2y[k3][k2],  dy[k2][k1][k0]*b2x[k3][k2]);
  }

  // ---- per-pass BYTE bases (round-3 verified) -----------------------------
  const int m4 = (tid >> 4) & 1;
  const int bA = (tid ^ ((tid >> 4) & 15)) << 3;
  const int bB = ((tid & 15) | (m4 << 4) | ((tid >> 4) << 8)) << 3;
  const int bC = (((tid & 15) | (tid << 4)) ^ (m4 << 4)) << 3;

#define WRITE_A  _Pragma("unroll") for (int k = 0; k < 16; ++k) \
    *(float2*)(stb + ((bA ^ ((k & 1) << 7)) | (k << 11))) = s[k];
#define READ_B   _Pragma("unroll") for (int k = 0; k < 16; ++k) \
    s[k] = *(const float2*)(stb + (bB ^ (136 * k)));
#define WRITE_B  _Pragma("unroll") for (int k = 0; k < 16; ++k) \
    *(float2*)(stb + (bB ^ (136 * k))) = s[k];
#define READ_C   _Pragma("unroll") for (int k = 0; k < 16; ++k) \
    s[k] = *(const float2*)(stb + (bC ^ (k << 3)));

  // ================= layer 1 (the only state-vector gate passes) ===========
  gate_on_bit<0>(s, U1s + 3*8);        // ownership A: reg bit j <-> wire 3-j
  gate_on_bit<1>(s, U1s + 2*8);
  gate_on_bit<2>(s, U1s + 1*8);
  gate_on_bit<3>(s, U1s + 0*8);
  WRITE_A;
  __syncthreads();
  READ_B;                              // ownership B: reg bit j <-> wire 7-j
  gate_on_bit<0>(s, U1s + 7*8);
  gate_on_bit<1>(s, U1s + 6*8);
  gate_on_bit<2>(s, U1s + 5*8);
  gate_on_bit<3>(s, U1s + 4*8);
  WRITE_B;                             // same slots just read: no barrier
  __syncthreads();
  READ_C;                              // ownership C: reg bit j <-> wire 11-j
  gate_on_bit<0>(s, U1s + 11*8);
  gate_on_bit<1>(s, U1s + 10*8);
  gate_on_bit<2>(s, U1s +  9*8);
  gate_on_bit<3>(s, U1s +  8*8);

  // ---- output: layer-1 ring as index map; Walsh over k (round-3 verified) -
  const int ft = Fmap(tid << 4);
  float p2[16];
#pragma unroll
  for (int k = 0; k < 16; ++k) p2[k] = fmaf(s[k].x, s[k].x, s[k].y*s[k].y);
  float u8[8], v8[8];
#pragma unroll
  for (int l = 0; l < 8; ++l){ u8[l] = p2[l] + p2[l+8]; v8[l] = p2[l] - p2[l+8]; }
  const float T  = ((u8[0]+u8[1])+(u8[2]+u8[3])) + ((u8[4]+u8[5])+(u8[6]+u8[7]));
  const float S3 = ((v8[0]+v8[1])+(v8[2]+v8[3])) + ((v8[4]+v8[5])+(v8[6]+v8[7]));
  float a4[4];
#pragma unroll
  for (int l = 0; l < 4; ++l) a4[l] = v8[l] - v8[l+4];
  const float S23   = (a4[0]+a4[1]) + (a4[2]+a4[3]);
  const float b0 = a4[0]-a4[2], b1 = a4[1]-a4[3];
  const float S123  = b0 + b1;
  const float S0123 = b0 - b1;

  float r[NQ];
  r[0]  = sgnf(S0123, (ft >> 11) & 1);
#pragma unroll
  for (int w = 1; w <= 7; ++w)
    r[w] = sgnf(T, (ft >> (11 - w)) & 1);
  r[8]  = sgnf(S3,    (ft >> 3) & 1);
  r[9]  = sgnf(S23,   (ft >> 2) & 1);
  r[10] = sgnf(S123,  (ft >> 1) & 1);
  r[11] = sgnf(S0123,  ft       & 1);

  // ---- block reduction (round-3 verified) ---------------------------------
#pragma unroll
  for (int off = 32; off; off >>= 1)
#pragma unroll
    for (int w = 0; w < NQ; ++w) r[w] += __shfl_down(r[w], off);
  __syncthreads();
  const int wid = tid >> 6;
  if (lane == 0){
#pragma unroll
    for (int w = 0; w < NQ; ++w) red[wid*NQ + w] = r[w];
  }
  __syncthreads();
  if (tid < NQ)
    out[b*NQ + tid] = red[tid] + red[NQ + tid] + red[2*NQ + tid] + red[3*NQ + tid];
}

extern "C" void kernel_launch(void* const* d_in, const int* in_sizes, int n_in,
                              void* d_out, int out_size, void* d_ws, size_t ws_size,
                              hipStream_t stream){
  const float* x = (const float*)d_in[0];
  const float* w = (const float*)d_in[1];
  float* out = (float*)d_out;
  const int B = in_sizes[0] / NQ;     // 2048

  qsim_kernel<<<B, 256, 0, stream>>>(x, w, out);
}

// Round 13
// 59.433 us; speedup vs baseline: 1.3267x; 1.3267x over previous
//
#include <hip/hip_runtime.h>
#include <math.h>

#define NQ 12

// ============================================================================
// Transfer-matrix reformulation.
// Circuit = P · (⊗U1) · P · (⊗ v_p) |0..0>,  P: ring perm |i> -> |F(i)>,
//   F(y)_p = y_p^..^y_11 (p<=10), F(y)_11 = y_0^..^y_10   (verified r1-r9)
//   G=F^-1: G_p = y_p^y_{p+1} (p<=9), G_10 = y_10^y_11^y_0, G_11 = y_11^y_0.
// <Z_w> = sum_{k,l} conj(psi0[G(k)]) prod_q N_q[k_q,l_q] psi0[G(l)],
//   N_q = M_q = U1^dag Z U1 (wire 11-q) for q in S_w, else I;
//   S_w = {11-w..11} for w>=1, {0..10} for w=0  (suffix supports of F bits).
// psi0 = prod_p v_p  (product state after layer-0 1q gates; v = U0*(c,s)).
// G couples only neighbors (+ ring wrap through bit 0) -> 12-site chain with
// 4-dim complex bond (k_p,l_p); wrap handled by branching on (k_0,l_0)=(κ,λ);
// val(λ,κ)=conj(val(κ,λ)) => 3 branches: val00 + val11 + 2*Re(val01).
// Per-site factor: rho_p[a,b] = conj(v_p[a]) v_p[b]  (r00,r11 real, r01 cplx).
// Transition p->p+1: T'[k',l'] = (Σ_{k,l} T[k,l] rho_p[k^k', l^l']) N_{p+1}[k',l'];
// the κ/λ XOR in rho_10/rho_11 == swapping T rows/cols by κ/λ (verified alg.).
// ============================================================================

__global__ __launch_bounds__(192)
void tm_kernel(const float* __restrict__ x, const float* __restrict__ wts,
               float* __restrict__ out, int B){
  __shared__ float MsL[NQ*4];       // bit q: {m00, m01x, m01y, m11} (Hermitian)
  __shared__ float U0L[NQ*8];       // bit p: fused layer-0 U (complex 2x2)
  __shared__ float4 rhoS[16][NQ];   // (sample, bit p): {r00, r01x, r01y, r11}
  const int t = threadIdx.x;

  // ---- phase A: per-block gate prep (verified fused Rz*Ry*Rx math) --------
  if (t < 24){
    const int isL0 = (t >= 12);
    const int w = isL0 ? (t - 12) : t;
    const int layer = isL0 ? 0 : 1;
    const float ax = 0.5f * wts[layer*36 + w*3 + 0];
    const float ay = 0.5f * wts[layer*36 + w*3 + 1];
    const float az = 0.5f * wts[layer*36 + w*3 + 2];
    const float ca = cosf(ax), sa = sinf(ax);
    const float cb = cosf(ay), sb = sinf(ay);
    const float cc = cosf(az), sc = sinf(az);
    const float m00x =  cb*ca, m00y =  sb*sa;
    const float m01x = -sb*ca, m01y = -cb*sa;
    const float m10x =  sb*ca, m10y = -cb*sa;
    const float m11x =  cb*ca, m11y = -sb*sa;
    const float o0 = cc*m00x + sc*m00y, o1 = cc*m00y - sc*m00x;
    const float o2 = cc*m01x + sc*m01y, o3 = cc*m01y - sc*m01x;
    const float o4 = cc*m10x - sc*m10y, o5 = cc*m10y + sc*m10x;
    const float o6 = cc*m11x - sc*m11y, o7 = cc*m11y + sc*m11x;
    const int p = 11 - w;
    if (isL0){
      float* o = U0L + p*8;
      o[0]=o0; o[1]=o1; o[2]=o2; o[3]=o3; o[4]=o4; o[5]=o5; o[6]=o6; o[7]=o7;
    } else {
      // M = U1^dag Z U1: m00=|u00|^2-|u10|^2, m11=|u01|^2-|u11|^2,
      // m01 = conj(u00)u01 - conj(u10)u11
      float* m = MsL + p*4;
      m[0] = o0*o0 + o1*o1 - o4*o4 - o5*o5;
      m[1] = o0*o2 + o1*o3 - o4*o6 - o5*o7;
      m[2] = o0*o3 - o1*o2 - o4*o7 + o5*o6;
      m[3] = o2*o2 + o3*o3 - o6*o6 - o7*o7;
    }
  }
  __syncthreads();

  const int s  = t / NQ;                 // sample slot in block (0..15)
  const int j  = t % NQ;                 // wire index
  const int sg = blockIdx.x * 16 + s;    // global sample
  const int p  = 11 - j;                 // bit position of wire j

  // ---- phase B: per-(sample,bit) rho table --------------------------------
  if (sg < B){
    float c0, s0;
    sincosf(x[sg*NQ + j] * 1.5707963267948966f, &s0, &c0);
    const float* o = U0L + p*8;
    const float v0x = fmaf(o[0], c0, o[2]*s0);
    const float v0y = fmaf(o[1], c0, o[3]*s0);
    const float v1x = fmaf(o[4], c0, o[6]*s0);
    const float v1y = fmaf(o[5], c0, o[7]*s0);
    rhoS[s][p] = make_float4(fmaf(v0x,v0x, v0y*v0y),
                             fmaf(v0x,v1x, v0y*v1y),
                             fmaf(v0x,v1y, -v0y*v1x),
                             fmaf(v1x,v1x, v1y*v1y));
  }
  __syncthreads();
  if (sg >= B) return;

  // ---- phase C: 12-site contraction for (sample s, wire j) ----------------
  const int mask = (j == 0) ? 0x7FF : ((0xFFF << (11 - j)) & 0xFFF);
  float fA[12], fBx[12], fBy[12], fC[12];       // effective N per site (M or I)
#pragma unroll
  for (int q = 0; q < 12; ++q){
    const bool u = (mask >> q) & 1;
    fA[q]  = u ? MsL[q*4+0] : 1.f;
    fBx[q] = u ? MsL[q*4+1] : 0.f;
    fBy[q] = u ? MsL[q*4+2] : 0.f;
    fC[q]  = u ? MsL[q*4+3] : 1.f;
  }
  float4 rp[12];
#pragma unroll
  for (int q = 0; q < 12; ++q) rp[q] = rhoS[s][q];

  float acc = 0.f;
#pragma unroll
  for (int b = 0; b < 3; ++b){                  // (κ,λ): (0,0),(1,1),(0,1)
    const bool kap = (b == 1), lam = (b != 0);
    const float wgt = (b == 2) ? 2.f : 1.f;
    // init: T[κ][λ] = N_0[κ][λ]
    float T00x = (b==0) ? fA[0]  : 0.f, T00y = 0.f;
    float T01x = (b==2) ? fBx[0] : 0.f, T01y = (b==2) ? fBy[0] : 0.f;
    float T10x = 0.f,                   T10y = 0.f;
    float T11x = (b==1) ? fC[0]  : 0.f, T11y = 0.f;
#pragma unroll
    for (int q = 0; q <= 10; ++q){
      if (q == 10){                             // absorb κ/λ XOR of rho_10
        if (kap){ float tx,ty;
          tx=T00x;ty=T00y; T00x=T10x;T00y=T10y; T10x=tx;T10y=ty;
          tx=T01x;ty=T01y; T01x=T11x;T01y=T11y; T11x=tx;T11y=ty; }
        if (lam){ float tx,ty;
          tx=T00x;ty=T00y; T00x=T01x;T00y=T01y; T01x=tx;T01y=ty;
          tx=T10x;ty=T10y; T10x=T11x;T10y=T11y; T11x=tx;T11y=ty; }
      }
      const float r0 = rp[q].x, rx = rp[q].y, ry = rp[q].z, r1 = rp[q].w;
      // inner[k',l'] = sum_{k,l} T[k,l] * rho[k^k', l^l']
      const float i00x = fmaf(T00x,r0, fmaf(T01x,rx, fmaf(-T01y,ry, fmaf(T10x,rx, fmaf( T10y,ry, T11x*r1)))));
      const float i00y = fmaf(T00y,r0, fmaf(T01x,ry, fmaf( T01y,rx, fmaf(T10y,rx, fmaf(-T10x,ry, T11y*r1)))));
      const float i01x = fmaf(T00x,rx, fmaf(-T00y,ry, fmaf(T01x,r0, fmaf(T10x,r1, fmaf(T11x,rx,  T11y*ry)))));
      const float i01y = fmaf(T00x,ry, fmaf( T00y,rx, fmaf(T01y,r0, fmaf(T10y,r1, fmaf(T11y,rx, -T11x*ry)))));
      const float i10x = fmaf(T00x,rx, fmaf( T00y,ry, fmaf(T01x,r1, fmaf(T10x,r0, fmaf(T11x,rx, -T11y*ry)))));
      const float i10y = fmaf(T00y,rx, fmaf(-T00x,ry, fmaf(T01y,r1, fmaf(T10y,r0, fmaf(T11x,ry,  T11y*rx)))));
      const float i11x = fmaf(T00x,r1, fmaf(T01x,rx, fmaf( T01y,ry, fmaf(T10x,rx, fmaf(-T10y,ry, T11x*r0)))));
      const float i11y = fmaf(T00y,r1, fmaf(T01y,rx, fmaf(-T01x,ry, fmaf(T10x,ry, fmaf( T10y,rx, T11y*r0)))));
      // apply N_{q+1}: diag real, offdiag f01 / conj(f01)
      const float g0 = fA[q+1], gx = fBx[q+1], gy = fBy[q+1], g1 = fC[q+1];
      T00x = i00x*g0;  T00y = i00y*g0;
      T11x = i11x*g1;  T11y = i11y*g1;
      T01x = fmaf(i01x,gx, -i01y*gy);  T01y = fmaf(i01x,gy,  i01y*gx);
      T10x = fmaf(i10x,gx,  i10y*gy);  T10y = fmaf(i10y,gx, -i10x*gy);
    }
    // closure: absorb κ/λ XOR of rho_11, then Re(sum T[k,l] rho_11[k,l])
    if (kap){ float tx,ty;
      tx=T00x;ty=T00y; T00x=T10x;T00y=T10y; T10x=tx;T10y=ty;
      tx=T01x;ty=T01y; T01x=T11x;T01y=T11y; T11x=tx;T11y=ty; }
    if (lam){ float tx,ty;
      tx=T00x;ty=T00y; T00x=T01x;T00y=T01y; T01x=tx;T01y=ty;
      tx=T10x;ty=T10y; T10x=T11x;T10y=T11y; T11x=tx;T11y=ty; }
    const float r0 = rp[11].x, rx = rp[11].y, ry = rp[11].z, r1 = rp[11].w;
    const float cr = fmaf(T00x,r0, fmaf(T01x,rx, fmaf(-T01y,ry, fmaf(T10x,rx, fmaf(T10y,ry, T11x*r1)))));
    acc = fmaf(wgt, cr, acc);
  }
  out[sg*NQ + j] = acc;
}

extern "C" void kernel_launch(void* const* d_in, const int* in_sizes, int n_in,
                              void* d_out, int out_size, void* d_ws, size_t ws_size,
                              hipStream_t stream){
  const float* x = (const float*)d_in[0];
  const float* w = (const float*)d_in[1];
  float* out = (float*)d_out;
  const int B = in_sizes[0] / NQ;     // 2048
  const int blocks = (B + 15) / 16;   // 16 samples x 12 wires = 192 thr/block

  tm_kernel<<<blocks, 192, 0, stream>>>(x, w, out, B);
}